// Round 12
// baseline (194.799 us; speedup 1.0000x reference)
//
#include <hip/hip_runtime.h>
#include <math.h>

namespace {

constexpr int kB = 16, kL = 60, kNC = 80, kNA = 3, kNH = 76, kNW = 76, kNCH = 85;
constexpr int kPlane = kNH * kNW;              // 5776
constexpr int kCellsPerB = kNA * kPlane;       // 17328
constexpr int kBX = (kCellsPerB + 255) / 256;  // 68
constexpr int kNPart = kB * kBX;               // 1088
constexpr float kEps = 1e-16f;

// Static buffers (no ws_size dependence; fully rewritten every call).
__device__ float g_partials[kNPart];
__device__ unsigned g_ticket = 0;  // zero-init at load; reset by the closing block

// st row layout (12 floats = 48 B rows):
// [0..3] x1,y1,x2,y2  [4] area  [5] unused  [6] dx [7] dy [8] lw [9] lh [10] sc [11] cls(bits)
__device__ __forceinline__ float sigm(float x) { return 1.0f / (1.0f + expf(-x)); }
// BCE(sigmoid(x), t) = softplus(x) - t*x ; stable softplus:
__device__ __forceinline__ float softplus(float x) {
  return fmaxf(x, 0.0f) + log1pf(expf(-fabsf(x)));
}
__device__ __forceinline__ float anchW(int a) { return a == 0 ? 1.25f : (a == 1 ? 2.0f : 4.125f); }
__device__ __forceinline__ float anchH(int a) { return a == 0 ? 1.625f : (a == 1 ? 3.75f : 2.875f); }

// ---- single kernel: label prep (wave 0) + per-cell loss + last-block finalize ----
// grid = (68, B) x 256 ; block covers cells [blockIdx.x*256, +256) of batch b.
__global__ __launch_bounds__(256) void yolo_loss(const float* __restrict__ out,
                                                 const float* __restrict__ labels,
                                                 float* __restrict__ outp) {
  const int b = blockIdx.y;
  const int tid = threadIdx.x;
  const int cb0 = blockIdx.x * 256;  // first cell of this block
  __shared__ float st[kL][12];
  __shared__ int swin[256];  // winner label per cell of this block (-1 = none)
  __shared__ int snv;
  __shared__ int sLast;

  swin[tid] = -1;

  int mykey = -1;  // wave-0 lane's scatter key (computed pre-barrier, used post)
  if (tid < 64) {  // wave 0: per-label prep (19 KB total labels -> L2-resident)
    const int l = tid;
    const bool in = l < kL;
    float c0 = 0.f, x = 0.f, y = 0.f, w = 0.f, h = 0.f;
    if (in) {
      const float* p = labels + ((size_t)b * kL + l) * 5;
      c0 = p[0]; x = p[1]; y = p[2]; w = p[3]; h = p[4];
    }
    // n_valid = count of rows with sum>0 ; valid = l < n_valid (prefix, ref quirk)
    const unsigned long long m = __ballot(in && (c0 + x + y + w + h > 0.0f));
    const int nv = __popcll(m);
    if (l == 0) snv = nv;
    if (in) {
      const bool valid = l < nv;
      const float tx = x * (float)kNW, ty = y * (float)kNH;
      const float tw = w * (float)kNW, th = h * (float)kNH;
      const int ti = (int)tx, tj = (int)ty;
      // CIoU of [0,0,tw,th] vs [0,0,aw,ah] (xyxy path), first-max argmax
      const float at0 = atanf(tw / fmaxf(th, kEps));
      float best = -INFINITY;
      int bn = 0;
#pragma unroll
      for (int k = 0; k < kNA; ++k) {
        const float aw = anchW(k), ah = anchH(k);
        const float miw = fminf(tw, aw), mih = fminf(th, ah);
        const float en = ((0.0f < miw) && (0.0f < mih)) ? 1.0f : 0.0f;
        const float ai = miw * mih * en;
        const float au = tw * th + aw * ah - ai;
        const float iou = ai / fmaxf(au, kEps);
        const float dw = tw - aw, dh = th - ah;
        const float rho2 = (dw * dw + dh * dh) * 0.25f;
        const float mw = fmaxf(tw, aw), mh = fmaxf(th, ah);
        const float c2 = mw * mw + mh * mh + kEps;
        const float da = at0 - atanf(aw / ah);
        const float v = (4.0f / (float)(M_PI * M_PI)) * da * da;
        const float alpha = v / fmaxf(1.0f - iou + v, kEps);
        const float ciou = iou - (rho2 / c2 + v * alpha);
        if (ciou > best) { best = ciou; bn = k; }
      }
      st[l][0] = tx - tw * 0.5f; st[l][1] = ty - th * 0.5f;
      st[l][2] = tx + tw * 0.5f; st[l][3] = ty + th * 0.5f;
      st[l][4] = tw * th;
      st[l][6] = tx - floorf(tx);
      st[l][7] = ty - floorf(ty);
      st[l][8] = logf(tw / anchW(bn) + kEps);
      st[l][9] = logf(th / anchH(bn) + kEps);
      st[l][10] = sqrtf(2.0f - tw * th * (1.0f / (float)(kNW * kNH)));
      st[l][11] = __int_as_float((int)c0);
      mykey = valid ? ((bn * kNH + tj) * kNW + ti) : -1;
    }
  }
  __syncthreads();  // swin init + st visible

  // wave 0 scatters winners into this block's table; atomicMax == last(-l)-wins,
  // matching the measured-correct collision rule (highest l overwrites).
  if (tid < kL && mykey >= cb0 && mykey < cb0 + 256) {
    atomicMax(&swin[mykey - cb0], tid);
  }
  __syncthreads();

  const int c = cb0 + tid;
  const bool active = c < kCellsPerB;
  const int cs = active ? c : 0;  // clamped for safe addressing on tail lanes
  const int winner = active ? swin[tid] : -1;

  const unsigned a = (unsigned)cs / (unsigned)kPlane;
  const unsigned r = (unsigned)cs - a * (unsigned)kPlane;
  const unsigned j = r / (unsigned)kNW;
  const unsigned i = r - j * (unsigned)kNW;
  const float* base = out + ((size_t)(b * kNA + (int)a) * kNCH) * kPlane + r;
  const float x0 = base[0];
  const float x1 = base[(size_t)kPlane];
  const float x2 = base[(size_t)2 * kPlane];
  const float x3 = base[(size_t)3 * kPlane];
  const float x4 = base[(size_t)4 * kPlane];

  // pred box (cx,cy,w,h) -> corners
  const float px = sigm(x0) + (float)i;
  const float py = sigm(x1) + (float)j;
  const float pw = expf(x2) * anchW((int)a);
  const float ph = expf(x3) * anchH((int)a);
  const float px1 = px - 0.5f * pw, px2 = px + 0.5f * pw;
  const float py1 = py - 0.5f * ph, py2 = py + 0.5f * ph;
  const float ap = pw * ph;

  // flag = (max IoU over valid targets) > 0.5  (key matching already done via swin)
  bool flag = false;
  const int nv = snv;
#pragma unroll 4
  for (int t = 0; t < nv; ++t) {
    const float4 bx = *reinterpret_cast<const float4*>(&st[t][0]);  // broadcast b128
    const float areaT = st[t][4];                                   // broadcast b32
    const float tlx = fmaxf(px1, bx.x), tly = fmaxf(py1, bx.y);
    const float brx = fminf(px2, bx.z), bry = fminf(py2, bx.w);
    const bool ok = (tlx < brx) && (tly < bry);
    const float ai = ok ? (brx - tlx) * (bry - tly) : 0.0f;
    flag = flag || (ai + ai > ap + areaT - ai);  // iou > 0.5 (division-free, exact)
  }

  float acc = 0.0f;
  if (active) {
    const float sp4 = softplus(x4);
    if (winner >= 0) {
      // scattered cell: obj_mask=1, tobj=1, plus xy/wh terms (cls handled below)
      acc += sp4 - x4;
      const float sc = st[winner][10];
      const float w2 = sc * sc;
      acc += (softplus(x0) - st[winner][6] * x0 + softplus(x1) - st[winner][7] * x1) * w2;
      const float d2 = x2 - st[winner][8], d3 = x3 - st[winner][9];
      acc += 0.5f * w2 * (d2 * d2 + d3 * d3);  // wh
    } else if (!flag) {
      acc += sp4;  // obj_mask=1 (best_iou<=0.5 or no valid targets), tobj=0
    }
    // else: obj_mask=0 -> contributes 0
  }

  // ---- wave-cooperative class loss for winner cells (<=960 total, ~0.9/wave) ----
  {
    const int lane = tid & 63;
    unsigned long long pend = __ballot(winner >= 0);
    while (pend) {
      const int src = (int)(__ffsll(pend) - 1);
      pend &= pend - 1;
      const int wc = __shfl(c, src);
      const int wt = __shfl(winner, src);
      const int cls = __float_as_int(st[wt][11]);  // uniform LDS addr -> broadcast
      const unsigned wa = (unsigned)wc / (unsigned)kPlane;
      const unsigned wr = (unsigned)wc - wa * (unsigned)kPlane;
      const float* wb = out + ((size_t)(b * kNA + (int)wa) * kNCH + 5) * kPlane + wr;
      const float v0 = wb[(size_t)lane * kPlane];
      float s = softplus(v0) - (lane == cls ? v0 : 0.0f);
      if (lane < kNC - 64) {  // lanes 0..15 also cover classes 64..79
        const float v1 = wb[(size_t)(lane + 64) * kPlane];
        s += softplus(v1) - (lane + 64 == cls ? v1 : 0.0f);
      }
#pragma unroll
      for (int off = 32; off > 0; off >>= 1) s += __shfl_down(s, off);
      if (lane == 0) acc += s;
    }
  }

  // deterministic block reduction
#pragma unroll
  for (int off = 32; off > 0; off >>= 1) acc += __shfl_down(acc, off);
  __shared__ float sred[4];
  if ((tid & 63) == 0) sred[tid >> 6] = acc;
  __syncthreads();

  // publish partial (agent-scope release) + take a ticket; last block finalizes
  const int pid = b * kBX + blockIdx.x;
  if (tid == 0) {
    const float part = sred[0] + sred[1] + sred[2] + sred[3];
    __hip_atomic_store(&g_partials[pid], part, __ATOMIC_RELEASE, __HIP_MEMORY_SCOPE_AGENT);
    const unsigned t = __hip_atomic_fetch_add(&g_ticket, 1u, __ATOMIC_ACQ_REL,
                                              __HIP_MEMORY_SCOPE_AGENT);
    sLast = (t == (unsigned)(kNPart - 1)) ? 1 : 0;
  }
  __syncthreads();

  if (sLast) {  // exactly one block; deterministic double-precision reduce
    double dacc = 0.0;
    for (int idx = tid; idx < kNPart; idx += 256) {
      const float pv = __hip_atomic_load(&g_partials[idx], __ATOMIC_ACQUIRE,
                                         __HIP_MEMORY_SCOPE_AGENT);
      dacc += (double)pv;
    }
    __shared__ double sd[256];
    sd[tid] = dacc;
    __syncthreads();
    for (int off = 128; off > 0; off >>= 1) {
      if (tid < off) sd[tid] += sd[tid + off];
      __syncthreads();
    }
    if (tid == 0) {
      outp[0] = (float)(sd[0] / (double)kB);
      __hip_atomic_store(&g_ticket, 0u, __ATOMIC_RELEASE, __HIP_MEMORY_SCOPE_AGENT);
    }
  }
}

}  // namespace

extern "C" void kernel_launch(void* const* d_in, const int* in_sizes, int n_in,
                              void* d_out, int out_size, void* d_ws, size_t ws_size,
                              hipStream_t stream) {
  const float* output = (const float*)d_in[0];  // (B, NA*85, 76, 76) f32
  const float* target = (const float*)d_in[1];  // (B, L, 5) f32
  float* outp = (float*)d_out;                  // scalar f32
  (void)d_ws; (void)ws_size;                    // workspace unused (static buffers)

  yolo_loss<<<dim3(kBX, kB), 256, 0, stream>>>(output, target, outp);
}

// Round 13
// 139.491 us; speedup vs baseline: 1.3965x; 1.3965x over previous
//
#include <hip/hip_runtime.h>
#include <math.h>

namespace {

constexpr int kB = 16, kL = 60, kNC = 80, kNA = 3, kNH = 76, kNW = 76, kNCH = 85;
constexpr int kPlane = kNH * kNW;              // 5776
constexpr int kCellsPerB = kNA * kPlane;       // 17328
constexpr int kBX = (kCellsPerB + 255) / 256;  // 68
constexpr int kNPart = kB * kBX;               // 1088
constexpr float kEps = 1e-16f;

// Static partial-sum buffer (no ws_size dependence; fully rewritten every call).
__device__ float g_partials[kNPart];

// st row layout (12 floats = 48 B, 16B-aligned rows):
// [0..3] x1,y1,x2,y2  [4] area  [5] key(bits)  [6] dx [7] dy [8] lw [9] lh [10] sc [11] cls(bits)
__device__ __forceinline__ float sigm(float x) { return 1.0f / (1.0f + expf(-x)); }
// BCE(sigmoid(x), t) = softplus(x) - t*x ; stable softplus:
__device__ __forceinline__ float softplus(float x) {
  return fmaxf(x, 0.0f) + log1pf(expf(-fabsf(x)));
}
__device__ __forceinline__ float anchW(int a) { return a == 0 ? 1.25f : (a == 1 ? 2.0f : 4.125f); }
__device__ __forceinline__ float anchH(int a) { return a == 0 ? 1.625f : (a == 1 ? 3.75f : 2.875f); }

// ---- main: per-cell loss, label prep fused. grid = (68, B) x 256 ----
// Latency plan: 5 channel loads issued BEFORE the prep barrier (hide under wave-0
// prep); t-loop reads 4 targets per batch (grouped lgkmcnt wait, 4-way VALU ILP).
__global__ __launch_bounds__(256) void main_loss(const float* __restrict__ out,
                                                 const float* __restrict__ labels) {
  const int b = blockIdx.y;
  const int tid = threadIdx.x;
  const int c = blockIdx.x * 256 + tid;
  const bool active = c < kCellsPerB;
  const int cs = active ? c : 0;     // clamped for safe addressing on tail lanes
  const int ckey = active ? c : -9;  // never matches any key (-1 or >=0)

  // --- issue channel loads first; latency hides under label prep + barrier ---
  const unsigned a = (unsigned)cs / (unsigned)kPlane;
  const unsigned r = (unsigned)cs - a * (unsigned)kPlane;
  const unsigned j = r / (unsigned)kNW;
  const unsigned i = r - j * (unsigned)kNW;
  const float* base = out + ((size_t)(b * kNA + (int)a) * kNCH) * kPlane + r;
  const float x0 = base[0];
  const float x1 = base[(size_t)kPlane];
  const float x2 = base[(size_t)2 * kPlane];
  const float x3 = base[(size_t)3 * kPlane];
  const float x4 = base[(size_t)4 * kPlane];

  __shared__ float st[kL][12];
  __shared__ int snv;

  if (tid < 64) {  // wave 0: per-label prep (labels are 19 KB total -> L2-resident)
    const int l = tid;
    const bool in = l < kL;
    float c0 = 0.f, x = 0.f, y = 0.f, w = 0.f, h = 0.f;
    if (in) {
      const float* p = labels + ((size_t)b * kL + l) * 5;
      c0 = p[0]; x = p[1]; y = p[2]; w = p[3]; h = p[4];
    }
    // n_valid = count of rows with sum>0 ; valid = l < n_valid (prefix, ref quirk)
    const unsigned long long m = __ballot(in && (c0 + x + y + w + h > 0.0f));
    const int nv = __popcll(m);
    if (l == 0) snv = nv;
    if (in) {
      const bool valid = l < nv;
      const float tx = x * (float)kNW, ty = y * (float)kNH;
      const float tw = w * (float)kNW, th = h * (float)kNH;
      const int ti = (int)tx, tj = (int)ty;
      // CIoU of [0,0,tw,th] vs [0,0,aw,ah] (xyxy path), first-max argmax
      const float at0 = atanf(tw / fmaxf(th, kEps));
      float best = -INFINITY;
      int bn = 0;
#pragma unroll
      for (int k = 0; k < kNA; ++k) {
        const float aw = anchW(k), ah = anchH(k);
        const float miw = fminf(tw, aw), mih = fminf(th, ah);
        const float en = ((0.0f < miw) && (0.0f < mih)) ? 1.0f : 0.0f;
        const float ai = miw * mih * en;
        const float au = tw * th + aw * ah - ai;
        const float iou = ai / fmaxf(au, kEps);
        const float dw = tw - aw, dh = th - ah;
        const float rho2 = (dw * dw + dh * dh) * 0.25f;
        const float mw = fmaxf(tw, aw), mh = fmaxf(th, ah);
        const float c2 = mw * mw + mh * mh + kEps;
        const float da = at0 - atanf(aw / ah);
        const float v = (4.0f / (float)(M_PI * M_PI)) * da * da;
        const float alpha = v / fmaxf(1.0f - iou + v, kEps);
        const float ciou = iou - (rho2 / c2 + v * alpha);
        if (ciou > best) { best = ciou; bn = k; }
      }
      st[l][0] = tx - tw * 0.5f; st[l][1] = ty - th * 0.5f;
      st[l][2] = tx + tw * 0.5f; st[l][3] = ty + th * 0.5f;
      st[l][4] = tw * th;
      st[l][5] = __int_as_float(valid ? ((bn * kNH + tj) * kNW + ti) : -1);
      st[l][6] = tx - floorf(tx);
      st[l][7] = ty - floorf(ty);
      st[l][8] = logf(tw / anchW(bn) + kEps);
      st[l][9] = logf(th / anchH(bn) + kEps);
      st[l][10] = sqrtf(2.0f - tw * th * (1.0f / (float)(kNW * kNH)));
      st[l][11] = __int_as_float((int)c0);
    }
  }
  __syncthreads();

  // pred box (cx,cy,w,h) -> corners
  const float px = sigm(x0) + (float)i;
  const float py = sigm(x1) + (float)j;
  const float pw = expf(x2) * anchW((int)a);
  const float ph = expf(x3) * anchH((int)a);
  const float px1 = px - 0.5f * pw, px2 = px + 0.5f * pw;
  const float py1 = py - 0.5f * ph, py2 = py + 0.5f * ph;
  const float ap = pw * ph;

  // flag = (max IoU over valid targets) > 0.5 ; winner = last label hitting this cell.
  // 4-target register batches: 8 independent ds_reads -> one grouped wait -> 4 IoUs.
  bool flag = false;
  int winner = -1;
  const int nv = snv;
  int t = 0;
  for (; t + 4 <= nv; t += 4) {
    const float4 b0 = *reinterpret_cast<const float4*>(&st[t + 0][0]);
    const float2 k0 = *reinterpret_cast<const float2*>(&st[t + 0][4]);
    const float4 b1 = *reinterpret_cast<const float4*>(&st[t + 1][0]);
    const float2 k1 = *reinterpret_cast<const float2*>(&st[t + 1][4]);
    const float4 b2 = *reinterpret_cast<const float4*>(&st[t + 2][0]);
    const float2 k2 = *reinterpret_cast<const float2*>(&st[t + 2][4]);
    const float4 b3 = *reinterpret_cast<const float4*>(&st[t + 3][0]);
    const float2 k3 = *reinterpret_cast<const float2*>(&st[t + 3][4]);
    {
      const float tlx = fmaxf(px1, b0.x), tly = fmaxf(py1, b0.y);
      const float brx = fminf(px2, b0.z), bry = fminf(py2, b0.w);
      const float ai = ((tlx < brx) && (tly < bry)) ? (brx - tlx) * (bry - tly) : 0.0f;
      flag = flag || (ai + ai > ap + k0.x - ai);
      if (__float_as_int(k0.y) == ckey) winner = t + 0;
    }
    {
      const float tlx = fmaxf(px1, b1.x), tly = fmaxf(py1, b1.y);
      const float brx = fminf(px2, b1.z), bry = fminf(py2, b1.w);
      const float ai = ((tlx < brx) && (tly < bry)) ? (brx - tlx) * (bry - tly) : 0.0f;
      flag = flag || (ai + ai > ap + k1.x - ai);
      if (__float_as_int(k1.y) == ckey) winner = t + 1;
    }
    {
      const float tlx = fmaxf(px1, b2.x), tly = fmaxf(py1, b2.y);
      const float brx = fminf(px2, b2.z), bry = fminf(py2, b2.w);
      const float ai = ((tlx < brx) && (tly < bry)) ? (brx - tlx) * (bry - tly) : 0.0f;
      flag = flag || (ai + ai > ap + k2.x - ai);
      if (__float_as_int(k2.y) == ckey) winner = t + 2;
    }
    {
      const float tlx = fmaxf(px1, b3.x), tly = fmaxf(py1, b3.y);
      const float brx = fminf(px2, b3.z), bry = fminf(py2, b3.w);
      const float ai = ((tlx < brx) && (tly < bry)) ? (brx - tlx) * (bry - tly) : 0.0f;
      flag = flag || (ai + ai > ap + k3.x - ai);
      if (__float_as_int(k3.y) == ckey) winner = t + 3;
    }
  }
  for (; t < nv; ++t) {  // remainder (<=3)
    const float4 bx = *reinterpret_cast<const float4*>(&st[t][0]);
    const float2 ak = *reinterpret_cast<const float2*>(&st[t][4]);
    const float tlx = fmaxf(px1, bx.x), tly = fmaxf(py1, bx.y);
    const float brx = fminf(px2, bx.z), bry = fminf(py2, bx.w);
    const float ai = ((tlx < brx) && (tly < bry)) ? (brx - tlx) * (bry - tly) : 0.0f;
    flag = flag || (ai + ai > ap + ak.x - ai);
    if (__float_as_int(ak.y) == ckey) winner = t;
  }

  float acc = 0.0f;
  if (active) {
    const float sp4 = softplus(x4);
    if (winner >= 0) {
      // scattered cell: obj_mask=1, tobj=1, plus xy/wh terms (cls handled below)
      acc += sp4 - x4;
      const float sc = st[winner][10];
      const float w2 = sc * sc;
      acc += (softplus(x0) - st[winner][6] * x0 + softplus(x1) - st[winner][7] * x1) * w2;
      const float d2 = x2 - st[winner][8], d3 = x3 - st[winner][9];
      acc += 0.5f * w2 * (d2 * d2 + d3 * d3);  // wh
    } else if (!flag) {
      acc += sp4;  // obj_mask=1 (best_iou<=0.5 or no valid targets), tobj=0
    }
    // else: obj_mask=0 -> contributes 0
  }

  // ---- wave-cooperative class loss for winner cells (<=960 total, ~0.9/wave) ----
  {
    const int lane = tid & 63;
    unsigned long long pend = __ballot(winner >= 0);
    while (pend) {
      const int src = (int)(__ffsll(pend) - 1);
      pend &= pend - 1;
      const int wc = __shfl(c, src);
      const int wt = __shfl(winner, src);
      const int cls = __float_as_int(st[wt][11]);  // uniform LDS addr -> broadcast
      const unsigned wa = (unsigned)wc / (unsigned)kPlane;
      const unsigned wr = (unsigned)wc - wa * (unsigned)kPlane;
      const float* wb = out + ((size_t)(b * kNA + (int)wa) * kNCH + 5) * kPlane + wr;
      const float v0 = wb[(size_t)lane * kPlane];
      float s = softplus(v0) - (lane == cls ? v0 : 0.0f);
      if (lane < kNC - 64) {  // lanes 0..15 also cover classes 64..79
        const float v1 = wb[(size_t)(lane + 64) * kPlane];
        s += softplus(v1) - (lane + 64 == cls ? v1 : 0.0f);
      }
#pragma unroll
      for (int off = 32; off > 0; off >>= 1) s += __shfl_down(s, off);
      if (lane == 0) acc += s;
    }
  }

  // deterministic block reduction (wave shfl + tiny LDS)
#pragma unroll
  for (int off = 32; off > 0; off >>= 1) acc += __shfl_down(acc, off);
  __shared__ float sred[4];
  if ((tid & 63) == 0) sred[tid >> 6] = acc;
  __syncthreads();
  if (tid == 0) g_partials[b * kBX + blockIdx.x] = sred[0] + sred[1] + sred[2] + sred[3];
}

// ---------------- final deterministic reduce ----------------
__global__ void finalize(float* __restrict__ outp) {
  const int tid = threadIdx.x;
  double acc = 0.0;
  for (int idx = tid; idx < kNPart; idx += 256) acc += (double)g_partials[idx];
  __shared__ double s[256];
  s[tid] = acc;
  __syncthreads();
  for (int off = 128; off > 0; off >>= 1) {
    if (tid < off) s[tid] += s[tid + off];
    __syncthreads();
  }
  if (tid == 0) outp[0] = (float)(s[0] / (double)kB);
}

}  // namespace

extern "C" void kernel_launch(void* const* d_in, const int* in_sizes, int n_in,
                              void* d_out, int out_size, void* d_ws, size_t ws_size,
                              hipStream_t stream) {
  const float* output = (const float*)d_in[0];  // (B, NA*85, 76, 76) f32
  const float* target = (const float*)d_in[1];  // (B, L, 5) f32
  float* outp = (float*)d_out;                  // scalar f32
  (void)d_ws; (void)ws_size;                    // workspace unused (static buffers)

  main_loss<<<dim3(kBX, kB), 256, 0, stream>>>(output, target);
  finalize<<<1, 256, 0, stream>>>(outp);
}